// Round 1
// baseline (475.898 us; speedup 1.0000x reference)
//
#include <hip/hip_runtime.h>
#include <cstdint>
#include <math.h>

#define BM 16     // rows per block
#define TJ 256    // j-tile (64 lanes * float4)

// Skinny GEMM: Y[row][k] = sum_j A[row][j] * MT[k][j]   (MT is the K x nj transposed operand)
// Block: 256 threads = 4 waves; wave w owns rows row0+4w..+3; lanes stride j by float4.
// MT j-tiles staged to LDS via global_load_lds(16B), double-buffered.
// EPI 0: store Y transposed to out[K][ldo]                     (kernel: M1T = (X@W1)^T)
// EPI 1: h=relu(Y+bias); out[k2][row] = sum_k h[k]*W2[k][k2]   (kernel: P^T = (relu(A@M1+b1)@W2)^T)
// EPI 2: out[row*8+k] = relu(Y+bias)                           (kernel: z row-major)
template<int K, int EPI>
__launch_bounds__(256, 2)
__global__ void skinny_gemm(const float* __restrict__ A, int lda, int nj,
                            const float* __restrict__ MT, int ldm,
                            float* __restrict__ out, int ldo,
                            const float* __restrict__ bias,
                            const float* __restrict__ W2)
{
    __shared__ float lds[2][K][TJ];
    const int tid  = threadIdx.x;
    const int lane = tid & 63;
    const int wave = tid >> 6;
    const int row0 = blockIdx.x * BM;

    float acc[4][K];
#pragma unroll
    for (int r = 0; r < 4; ++r)
#pragma unroll
        for (int k = 0; k < K; ++k) acc[r][k] = 0.f;

    const int ntiles = nj / TJ;

    // stage tile 0 -> buf 0 (each wave stages K/4 rows; dest = uniform row base + lane*16)
#pragma unroll
    for (int i = 0; i < K / 4; ++i) {
        const int k = wave + i * 4;
        const float* g = MT + (size_t)k * ldm + lane * 4;
        __builtin_amdgcn_global_load_lds(
            (const __attribute__((address_space(1))) void*)g,
            (__attribute__((address_space(3))) void*)(&lds[0][k][0]), 16, 0, 0);
    }

    const float* arow[4];
#pragma unroll
    for (int r = 0; r < 4; ++r)
        arow[r] = A + (size_t)(row0 + wave * 4 + r) * lda;

    for (int t = 0; t < ntiles; ++t) {
        __syncthreads();                // staging of buf (t&1) complete, prev compute done
        const int buf = t & 1;
        if (t + 1 < ntiles) {
#pragma unroll
            for (int i = 0; i < K / 4; ++i) {
                const int k = wave + i * 4;
                const float* g = MT + (size_t)k * ldm + (size_t)(t + 1) * TJ + lane * 4;
                __builtin_amdgcn_global_load_lds(
                    (const __attribute__((address_space(1))) void*)g,
                    (__attribute__((address_space(3))) void*)(&lds[buf ^ 1][k][0]), 16, 0, 0);
            }
        }
        float4 a[4];
#pragma unroll
        for (int r = 0; r < 4; ++r)
            a[r] = *(const float4*)(arow[r] + (size_t)t * TJ + lane * 4);
#pragma unroll
        for (int k = 0; k < K; ++k) {
            const float4 m = *(const float4*)&lds[buf][k][lane * 4];
#pragma unroll
            for (int r = 0; r < 4; ++r)
                acc[r][k] += a[r].x * m.x + a[r].y * m.y + a[r].z * m.z + a[r].w * m.w;
        }
    }

    // butterfly reduce over 64 lanes: every lane ends with the full sums
#pragma unroll
    for (int s = 1; s < 64; s <<= 1)
#pragma unroll
        for (int r = 0; r < 4; ++r)
#pragma unroll
            for (int k = 0; k < K; ++k)
                acc[r][k] += __shfl_xor(acc[r][k], s, 64);

    if (EPI == 0) {
        if (lane < K) {
#pragma unroll
            for (int r = 0; r < 4; ++r) {
                float v = acc[r][0];
#pragma unroll
                for (int k = 1; k < K; ++k) if (lane == k) v = acc[r][k];
                out[(size_t)lane * ldo + row0 + wave * 4 + r] = v;
            }
        }
    } else if (EPI == 1) {
        if (lane < 8) {
#pragma unroll
            for (int r = 0; r < 4; ++r) {
                float p = 0.f;
#pragma unroll
                for (int k = 0; k < K; ++k) {
                    float h = acc[r][k] + bias[k];
                    h = h > 0.f ? h : 0.f;
                    p += h * W2[k * 8 + lane];
                }
                out[(size_t)lane * ldo + row0 + wave * 4 + r] = p;
            }
        }
    } else { // EPI == 2
        if (lane < 8) {
#pragma unroll
            for (int r = 0; r < 4; ++r) {
                float v = acc[r][0];
#pragma unroll
                for (int k = 1; k < K; ++k) if (lane == k) v = acc[r][k];
                v += bias[lane];
                v = v > 0.f ? v : 0.f;
                out[(size_t)(row0 + wave * 4 + r) * 8 + lane] = v;
            }
        }
    }
}

__global__ void transpose_w1(const float* __restrict__ W1, float* __restrict__ W1T)
{
    const int i = blockIdx.x * 256 + threadIdx.x;   // 4096 elements
    const int k = i >> 8, c = i & 255;
    W1T[i] = W1[c * 16 + k];
}

__global__ void tree_epilogue(const float* __restrict__ z,      // [N][8] row-major
                              const float* __restrict__ Wd,     // [8][16]
                              const float* __restrict__ bd,     // [16]
                              const float* __restrict__ mask,   // [16][16]
                              const float* __restrict__ Wdec,   // [16][16]
                              const float* __restrict__ bdec,   // [16]
                              const float* __restrict__ pi,     // [16][10]
                              float* __restrict__ out)          // [N][10]
{
    const int row = blockIdx.x * blockDim.x + threadIdx.x;
    float zv[8];
#pragma unroll
    for (int k = 0; k < 8; ++k) zv[k] = z[(size_t)row * 8 + k];

    float feat[16];
#pragma unroll
    for (int f = 0; f < 16; ++f) {
        float s = bd[f];
#pragma unroll
        for (int k = 0; k < 8; ++k) s += zv[k] * Wd[k * 16 + f];
        feat[f] = s > 0.f ? s : 0.f;
    }
    float fm[16];
#pragma unroll
    for (int f = 0; f < 16; ++f) {
        float s = 0.f;
#pragma unroll
        for (int g = 0; g < 16; ++g) s += feat[g] * mask[g * 16 + f];
        fm[f] = s;
    }
    float mu[16];
#pragma unroll
    for (int j = 0; j < 8; ++j) {
        const int f = 8 + j;
        float s = bdec[f];
#pragma unroll
        for (int g = 0; g < 16; ++g) s += fm[g] * Wdec[g * 16 + f];
        const float d = 1.f / (1.f + expf(-s));
        mu[2 * j]     = fm[f] * d;
        mu[2 * j + 1] = fm[f] * (1.f - d);
    }
#pragma unroll
    for (int c = 0; c < 10; ++c) {
        float s = 0.f;
#pragma unroll
        for (int m = 0; m < 16; ++m) {
            float p = pi[m * 10 + c];
            p = p > 0.f ? p : 0.f;
            s += mu[m] * p;
        }
        out[(size_t)row * 10 + c] = s;
    }
}

extern "C" void kernel_launch(void* const* d_in, const int* in_sizes, int n_in,
                              void* d_out, int out_size, void* d_ws, size_t ws_size,
                              hipStream_t stream)
{
    const float* X    = (const float*)d_in[0];   // [8192][256]
    const float* A    = (const float*)d_in[1];   // [8192][8192]
    const float* W1   = (const float*)d_in[2];   // [256][16]
    const float* b1   = (const float*)d_in[3];   // [16]
    const float* W2   = (const float*)d_in[4];   // [16][8]
    const float* b2   = (const float*)d_in[5];   // [8]
    const float* Wd   = (const float*)d_in[6];   // [8][16]
    const float* bd   = (const float*)d_in[7];   // [16]
    const float* mask = (const float*)d_in[8];   // [16][16]
    const float* Wdec = (const float*)d_in[9];   // [16][16]
    const float* bdec = (const float*)d_in[10];  // [16]
    const float* pi   = (const float*)d_in[11];  // [16][10]
    float* out = (float*)d_out;

    char* ws = (char*)d_ws;
    float* W1T = (float*)ws;                                  // 16*256*4   = 16 KB
    float* M1T = (float*)(ws + 16 * 1024);                    // 16*8192*4  = 512 KB
    float* PT  = (float*)(ws + 16 * 1024 + 512 * 1024);       // 8*8192*4   = 256 KB
    float* z   = (float*)(ws + 16 * 1024 + 768 * 1024);       // 8192*8*4   = 256 KB

    const int N = 8192;

    // W1T[k][c] = W1[c][k]
    hipLaunchKernelGGL(transpose_w1, dim3(16), dim3(256), 0, stream, W1, W1T);
    // M1T = (X @ W1)^T                      [16][8192]
    hipLaunchKernelGGL((skinny_gemm<16, 0>), dim3(N / BM), dim3(256), 0, stream,
                       X, 256, 256, W1T, 256, M1T, N, (const float*)nullptr, (const float*)nullptr);
    // PT = (relu(A @ M1 + b1) @ W2)^T       [8][8192]
    hipLaunchKernelGGL((skinny_gemm<16, 1>), dim3(N / BM), dim3(256), 0, stream,
                       A, N, N, M1T, N, PT, N, b1, W2);
    // z = relu(A @ P + b2)                  [8192][8] row-major
    hipLaunchKernelGGL((skinny_gemm<8, 2>), dim3(N / BM), dim3(256), 0, stream,
                       A, N, N, PT, N, z, 8, b2, (const float*)nullptr);
    // tree + pi
    hipLaunchKernelGGL(tree_epilogue, dim3(N / 256), dim3(256), 0, stream,
                       z, Wd, bd, mask, Wdec, bdec, pi, out);
}